// Round 8
// baseline (276.028 us; speedup 1.0000x reference)
//
#include <hip/hip_runtime.h>
#include <hip/hip_fp16.h>

#define N_NODES 50000
#define N_EDGES 800000
#define D_FEAT 128
#define HIDDEN 96
#define N_CLASSES 10
#define N_GRAPHS 64
#define POOL_SLICES 16
#define SCAN_BLOCKS ((N_NODES + 255) / 256)   // 196

union F4H8 { float4 f; __half2 h[4]; };
union U2H4 { uint2 u; __half2 h[2]; };

__device__ inline uint2 pack4(float a, float b, float c, float d) {
    union { uint2 u; __half2 h[2]; } p;
    p.h[0] = __floats2half2_rn(a, b);
    p.h[1] = __floats2half2_rn(c, d);
    return p.u;
}

// ---------------- graph preprocessing ----------------

__global__ void k_init(int* __restrict__ deg_i, float* __restrict__ pooled) {
    int i = blockIdx.x * 256 + threadIdx.x;
    if (i < N_NODES) deg_i[i] = 0;
    if (i < N_GRAPHS * HIDDEN) pooled[i] = 0.f;
}

__global__ void k_deg(const int* __restrict__ dst, int* __restrict__ deg_i,
                      int* __restrict__ rank) {
    int e = blockIdx.x * 256 + threadIdx.x;
    if (e < N_EDGES) rank[e] = atomicAdd(&deg_i[dst[e]], 1);
}

__global__ __launch_bounds__(256) void k_partial(const int* __restrict__ deg_i,
                                                 int* __restrict__ bsum) {
    __shared__ int wsum[4];
    int i = blockIdx.x * 256 + threadIdx.x;
    int v = (i < N_NODES) ? deg_i[i] : 0;
    for (int o = 32; o > 0; o >>= 1) v += __shfl_down(v, o, 64);
    int lane = threadIdx.x & 63, wid = threadIdx.x >> 6;
    if (lane == 0) wsum[wid] = v;
    __syncthreads();
    if (threadIdx.x == 0) bsum[blockIdx.x] = wsum[0] + wsum[1] + wsum[2] + wsum[3];
}

__global__ __launch_bounds__(256) void k_scanblk(const int* __restrict__ bsum,
                                                 int* __restrict__ bpre) {
    __shared__ int s[256];
    int t = threadIdx.x;
    s[t] = (t < SCAN_BLOCKS) ? bsum[t] : 0;
    __syncthreads();
    for (int off = 1; off < 256; off <<= 1) {
        int v = s[t];
        int a = (t >= off) ? s[t - off] : 0;
        __syncthreads();
        s[t] = v + a;
        __syncthreads();
    }
    if (t <= SCAN_BLOCKS) bpre[t] = (t == 0) ? 0 : s[t - 1];  // exclusive
}

__global__ __launch_bounds__(256) void k_offs(const int* __restrict__ deg_i,
                                              const int* __restrict__ bpre,
                                              int* __restrict__ offs,
                                              float* __restrict__ dinv) {
    __shared__ int s[256];
    int t = threadIdx.x;
    int i = blockIdx.x * 256 + t;
    int d = (i < N_NODES) ? deg_i[i] : 0;
    s[t] = d;
    __syncthreads();
    for (int off = 1; off < 256; off <<= 1) {
        int v = s[t];
        int a = (t >= off) ? s[t - off] : 0;
        __syncthreads();
        s[t] = v + a;
        __syncthreads();
    }
    int incl = s[t];
    int excl = incl - d;
    if (i < N_NODES) {
        int o = bpre[blockIdx.x] + excl;
        offs[i] = o;
        dinv[i] = rsqrtf((float)(d + 1));  // +1 self-loop
        if (i == N_NODES - 1) offs[N_NODES] = o + d;
    }
}

__global__ void k_fill(const int* __restrict__ src, const int* __restrict__ dst,
                       const int* __restrict__ rank, const int* __restrict__ offs,
                       int* __restrict__ csr_src) {
    int e = blockIdx.x * 256 + threadIdx.x;
    if (e >= N_EDGES) return;
    csr_src[offs[dst[e]] + rank[e]] = src[e];
}

// ---------------- x f32 -> fp16 (coalesced) ----------------

__global__ __launch_bounds__(256) void k_cvt(const float* __restrict__ x,
                                             __half* __restrict__ xh) {
    int idx = blockIdx.x * 256 + threadIdx.x;
    if (idx >= N_NODES * D_FEAT / 8) return;
    const float4* x4 = (const float4*)x;
    float4 a = x4[idx * 2], b = x4[idx * 2 + 1];
    F4H8 o;
    o.h[0] = __floats2half2_rn(a.x, a.y);
    o.h[1] = __floats2half2_rn(a.z, a.w);
    o.h[2] = __floats2half2_rn(b.x, b.y);
    o.h[3] = __floats2half2_rn(b.z, b.w);
    ((float4*)xh)[idx] = o.f;
}

// ---------------- matmul: hws = (h @ W) * dinv ----------------
// fp16 in / fp16 out, f32 accumulate. Block 256 thr, tile 64 nodes.
// h tile LDS-staged (coalesced, rows padded to 256B, XOR-swizzled -> 2-way max).
// W fp16 in LDS; inner reads uniform per half-wave (broadcast).
// thread (i=t&31, j=t>>5): nodes {base+i, base+i+32}, feats j*12..j*12+11.

#define FMA12(HQ, W0, W1, W2, R)                                        \
    acc[R][0].x += (HQ) * (W0).x; acc[R][0].y += (HQ) * (W0).y;         \
    acc[R][0].z += (HQ) * (W0).z; acc[R][0].w += (HQ) * (W0).w;         \
    acc[R][1].x += (HQ) * (W1).x; acc[R][1].y += (HQ) * (W1).y;         \
    acc[R][1].z += (HQ) * (W1).z; acc[R][1].w += (HQ) * (W1).w;         \
    acc[R][2].x += (HQ) * (W2).x; acc[R][2].y += (HQ) * (W2).y;         \
    acc[R][2].z += (HQ) * (W2).z; acc[R][2].w += (HQ) * (W2).w;

__device__ inline void store_row_fp16(__half* dst, const float4 a0, const float4 a1,
                                      const float4 a2, float dv) {
    uint2* d2 = (uint2*)dst;
    d2[0] = pack4(a0.x * dv, a0.y * dv, a0.z * dv, a0.w * dv);
    d2[1] = pack4(a1.x * dv, a1.y * dv, a1.z * dv, a1.w * dv);
    d2[2] = pack4(a2.x * dv, a2.y * dv, a2.z * dv, a2.w * dv);
}

template <int K>
__global__ __launch_bounds__(256) void k_mm_h(const __half* __restrict__ h,
                                              const float* __restrict__ W,
                                              const float* __restrict__ dinv,
                                              __half* __restrict__ hws) {
    constexpr int CH = K / 8;           // 16B chunks per input row
    __shared__ float4 Hl[64 * 16];      // 64 rows x 16 chunks (256B padded)
    __shared__ uint2  Wl[K * 24];       // K x 96 halfs
    int t = threadIdx.x;

    // stage W: f32 global -> fp16 LDS (coalesced)
    const float4* W4 = (const float4*)W;
    for (int idx = t; idx < K * 24; idx += 256) {
        float4 w = W4[idx];
        Wl[idx] = pack4(w.x, w.y, w.z, w.w);
    }
    // stage h tile (coalesced), swizzle chunk position by row
    const float4* h4 = (const float4*)h;
    int base = blockIdx.x * 64;
    for (int idx = t; idx < 64 * CH; idx += 256) {
        int row = idx / CH, c = idx % CH;
        int gr = base + row;
        if (gr >= N_NODES) gr = N_NODES - 1;
        Hl[row * 16 + (c ^ (row & 15))] = h4[(size_t)gr * CH + c];
    }
    __syncthreads();

    int i = t & 31, j = t >> 5;
    int jc = j * 3;   // uint2 offset within a W row = j*3 (12 halfs)
    float4 acc[2][3];
    #pragma unroll
    for (int r = 0; r < 2; ++r)
        #pragma unroll
        for (int c = 0; c < 3; ++c) acc[r][c] = make_float4(0.f, 0.f, 0.f, 0.f);

    for (int c8 = 0; c8 < CH; ++c8) {
        F4H8 ha, hb;
        ha.f = Hl[i * 16 + (c8 ^ (i & 15))];
        hb.f = Hl[(i + 32) * 16 + (c8 ^ (i & 15))];
        float fa[8], fb[8];
        #pragma unroll
        for (int q = 0; q < 4; ++q) {
            float2 pa = __half22float2(ha.h[q]);
            float2 pb = __half22float2(hb.h[q]);
            fa[2 * q] = pa.x; fa[2 * q + 1] = pa.y;
            fb[2 * q] = pb.x; fb[2 * q + 1] = pb.y;
        }
        int kw = (c8 * 8) * 24 + jc;
        #pragma unroll
        for (int q = 0; q < 8; ++q) {
            U2H4 u0, u1, u2;
            u0.u = Wl[kw]; u1.u = Wl[kw + 1]; u2.u = Wl[kw + 2];
            float2 q0 = __half22float2(u0.h[0]), q1 = __half22float2(u0.h[1]);
            float2 q2 = __half22float2(u1.h[0]), q3 = __half22float2(u1.h[1]);
            float2 q4 = __half22float2(u2.h[0]), q5 = __half22float2(u2.h[1]);
            float4 w0 = make_float4(q0.x, q0.y, q1.x, q1.y);
            float4 w1 = make_float4(q2.x, q2.y, q3.x, q3.y);
            float4 w2 = make_float4(q4.x, q4.y, q5.x, q5.y);
            FMA12(fa[q], w0, w1, w2, 0)
            FMA12(fb[q], w0, w1, w2, 1)
            kw += 24;
        }
    }

    int n = base + i;
    if (n < N_NODES)
        store_row_fp16(hws + (size_t)n * HIDDEN + j * 12,
                       acc[0][0], acc[0][1], acc[0][2], dinv[n]);
    n = base + i + 32;
    if (n < N_NODES)
        store_row_fp16(hws + (size_t)n * HIDDEN + j * 12,
                       acc[1][0], acc[1][1], acc[1][2], dinv[n]);
}

// ------------- aggregation: h_out[n] = relu(b + dinv[n]*(hws[n] + sum_in hws[s])) -------------

__global__ __launch_bounds__(256) void k_agg(const __half* __restrict__ hws,
                                             const float* __restrict__ dinv,
                                             const int* __restrict__ offs,
                                             const int* __restrict__ csr_src,
                                             const float* __restrict__ bias,
                                             __half* __restrict__ hout) {
    int id = blockIdx.x * 256 + threadIdx.x;
    if (id >= N_NODES * 12) return;
    int c = id % 12;
    int n = id / 12;
    const float4* hw4 = (const float4*)hws;
    F4H8 v;
    v.f = hw4[(size_t)n * 12 + c];   // self-loop (already dinv[n]-scaled)
    float2 p0 = __half22float2(v.h[0]), p1 = __half22float2(v.h[1]);
    float2 p2 = __half22float2(v.h[2]), p3 = __half22float2(v.h[3]);
    float4 A = make_float4(p0.x, p0.y, p1.x, p1.y);
    float4 B = make_float4(p2.x, p2.y, p3.x, p3.y);

    int beg = offs[n], end = offs[n + 1];
    int i = beg;
    for (; i + 2 <= end; i += 2) {
        F4H8 v0, v1;
        v0.f = hw4[(size_t)csr_src[i] * 12 + c];
        v1.f = hw4[(size_t)csr_src[i + 1] * 12 + c];
        float2 a0 = __half22float2(v0.h[0]), a1 = __half22float2(v0.h[1]);
        float2 a2 = __half22float2(v0.h[2]), a3 = __half22float2(v0.h[3]);
        float2 b0 = __half22float2(v1.h[0]), b1 = __half22float2(v1.h[1]);
        float2 b2 = __half22float2(v1.h[2]), b3 = __half22float2(v1.h[3]);
        A.x += a0.x + b0.x; A.y += a0.y + b0.y;
        A.z += a1.x + b1.x; A.w += a1.y + b1.y;
        B.x += a2.x + b2.x; B.y += a2.y + b2.y;
        B.z += a3.x + b3.x; B.w += a3.y + b3.y;
    }
    if (i < end) {
        F4H8 v0;
        v0.f = hw4[(size_t)csr_src[i] * 12 + c];
        float2 a0 = __half22float2(v0.h[0]), a1 = __half22float2(v0.h[1]);
        float2 a2 = __half22float2(v0.h[2]), a3 = __half22float2(v0.h[3]);
        A.x += a0.x; A.y += a0.y; A.z += a1.x; A.w += a1.y;
        B.x += a2.x; B.y += a2.y; B.z += a3.x; B.w += a3.y;
    }

    float di = dinv[n];
    float4 b0 = ((const float4*)bias)[c * 2];
    float4 b1 = ((const float4*)bias)[c * 2 + 1];
    A.x = fmaxf(A.x * di + b0.x, 0.f); A.y = fmaxf(A.y * di + b0.y, 0.f);
    A.z = fmaxf(A.z * di + b0.z, 0.f); A.w = fmaxf(A.w * di + b0.w, 0.f);
    B.x = fmaxf(B.x * di + b1.x, 0.f); B.y = fmaxf(B.y * di + b1.y, 0.f);
    B.z = fmaxf(B.z * di + b1.z, 0.f); B.w = fmaxf(B.w * di + b1.w, 0.f);

    F4H8 o;
    o.h[0] = __floats2half2_rn(A.x, A.y);
    o.h[1] = __floats2half2_rn(A.z, A.w);
    o.h[2] = __floats2half2_rn(B.x, B.y);
    o.h[3] = __floats2half2_rn(B.z, B.w);
    ((float4*)hout)[(size_t)n * 12 + c] = o.f;
}

// ------------- parallel mean-pool: 64 graphs x 16 slices (fp16 input) -------------

__global__ __launch_bounds__(192) void k_pool(const __half* __restrict__ h,
                                              const int* __restrict__ batch,
                                              float* __restrict__ pooled) {
    int g = blockIdx.x / POOL_SLICES;
    int slice = blockIdx.x % POOL_SLICES;
    int t = threadIdx.x;
    int f = t % HIDDEN;
    int j = t / HIDDEN;  // 0 or 1
    int lo = 0, hi = N_NODES;
    while (lo < hi) { int m = (lo + hi) >> 1; if (batch[m] < g) lo = m + 1; else hi = m; }
    int start = lo;
    hi = N_NODES;
    while (lo < hi) { int m = (lo + hi) >> 1; if (batch[m] < g + 1) lo = m + 1; else hi = m; }
    int end = lo;
    int len = end - start;
    int per = (len + POOL_SLICES - 1) / POOL_SLICES;
    int s0 = start + slice * per;
    int s1 = min(s0 + per, end);
    float acc = 0.f;
    for (int n = s0 + j; n < s1; n += 2) acc += __half2float(h[(size_t)n * HIDDEN + f]);
    atomicAdd(&pooled[g * HIDDEN + f], acc);
}

// ------------- MLP head, one block per graph -------------

__global__ __launch_bounds__(128) void k_head_mlp(const float* __restrict__ pooled_in,
                                                  const int* __restrict__ batch,
                                                  const float* __restrict__ lw1,
                                                  const float* __restrict__ lb1,
                                                  const float* __restrict__ lw2,
                                                  const float* __restrict__ lb2,
                                                  float* __restrict__ out) {
    __shared__ float pooled[HIDDEN];
    __shared__ float zbuf[HIDDEN];
    int g = blockIdx.x;
    int t = threadIdx.x;
    int lo = 0, hi = N_NODES;
    while (lo < hi) { int m = (lo + hi) >> 1; if (batch[m] < g) lo = m + 1; else hi = m; }
    int start = lo;
    hi = N_NODES;
    while (lo < hi) { int m = (lo + hi) >> 1; if (batch[m] < g + 1) lo = m + 1; else hi = m; }
    int end = lo;
    float cnt = fmaxf((float)(end - start), 1.f);
    if (t < HIDDEN) pooled[t] = pooled_in[g * HIDDEN + t] / cnt;
    __syncthreads();
    if (t < HIDDEN) {
        float a = lb1[t];
        for (int k = 0; k < HIDDEN; ++k) a += pooled[k] * lw1[k * HIDDEN + t];
        zbuf[t] = fmaxf(a, 0.f);
    }
    __syncthreads();
    if (t < N_CLASSES) {
        float a = lb2[t];
        for (int k = 0; k < HIDDEN; ++k) a += zbuf[k] * lw2[k * N_CLASSES + t];
        out[g * N_CLASSES + t] = a;
    }
}

// ---------------- launch ----------------

extern "C" void kernel_launch(void* const* d_in, const int* in_sizes, int n_in,
                              void* d_out, int out_size, void* d_ws, size_t ws_size,
                              hipStream_t stream) {
    const float* x   = (const float*)d_in[0];
    const int*   ei  = (const int*)d_in[1];   // [2, E]
    const int*   bat = (const int*)d_in[2];
    const float* W1  = (const float*)d_in[3];
    const float* b1  = (const float*)d_in[4];
    const float* W2  = (const float*)d_in[5];
    const float* b2  = (const float*)d_in[6];
    const float* W3  = (const float*)d_in[7];
    const float* b3  = (const float*)d_in[8];
    const float* lw1 = (const float*)d_in[9];
    const float* lb1 = (const float*)d_in[10];
    const float* lw2 = (const float*)d_in[11];
    const float* lb2 = (const float*)d_in[12];
    float* out = (float*)d_out;

    const int* src = ei;
    const int* dst = ei + N_EDGES;

    // workspace carve-up (256B aligned)
    char* ws = (char*)d_ws;
    size_t off = 0;
    auto alloc = [&](size_t bytes) {
        size_t p = off;
        off = (off + bytes + 255) & ~(size_t)255;
        return p;
    };
    float*  dinv    = (float*) (ws + alloc(sizeof(float) * N_NODES));
    int*    deg_i   = (int*)   (ws + alloc(sizeof(int) * N_NODES));
    int*    offs    = (int*)   (ws + alloc(sizeof(int) * (N_NODES + 1)));
    int*    bsum    = (int*)   (ws + alloc(sizeof(int) * (SCAN_BLOCKS + 1)));
    int*    bpre    = (int*)   (ws + alloc(sizeof(int) * (SCAN_BLOCKS + 1)));
    int*    rank    = (int*)   (ws + alloc(sizeof(int) * N_EDGES));
    int*    csr_src = (int*)   (ws + alloc(sizeof(int) * N_EDGES));
    __half* bufX    = (__half*)(ws + alloc(sizeof(__half) * (size_t)N_NODES * D_FEAT));
    __half* bufA    = (__half*)(ws + alloc(sizeof(__half) * (size_t)N_NODES * HIDDEN));
    __half* bufB    = (__half*)(ws + alloc(sizeof(__half) * (size_t)N_NODES * HIDDEN));
    float*  pooled  = (float*) (ws + alloc(sizeof(float) * N_GRAPHS * HIDDEN));
    (void)ws_size;

    const int nodeBlocks = (N_NODES + 255) / 256;
    const int edgeBlocks = (N_EDGES + 255) / 256;
    const int cvtBlocks  = (N_NODES * D_FEAT / 8 + 255) / 256;
    const int mmBlocks   = (N_NODES + 63) / 64;           // 782
    const int aggBlocks  = (N_NODES * 12 + 255) / 256;    // 2344

    k_init<<<nodeBlocks, 256, 0, stream>>>(deg_i, pooled);
    k_deg<<<edgeBlocks, 256, 0, stream>>>(dst, deg_i, rank);
    k_cvt<<<cvtBlocks, 256, 0, stream>>>(x, bufX);
    k_partial<<<SCAN_BLOCKS, 256, 0, stream>>>(deg_i, bsum);
    k_scanblk<<<1, 256, 0, stream>>>(bsum, bpre);
    k_offs<<<SCAN_BLOCKS, 256, 0, stream>>>(deg_i, bpre, offs, dinv);
    k_fill<<<edgeBlocks, 256, 0, stream>>>(src, dst, rank, offs, csr_src);

    // layer 1 (K=128)
    k_mm_h<D_FEAT><<<mmBlocks, 256, 0, stream>>>(bufX, W1, dinv, bufA);
    k_agg<<<aggBlocks, 256, 0, stream>>>(bufA, dinv, offs, csr_src, b1, bufB);
    // layer 2 (K=96)
    k_mm_h<HIDDEN><<<mmBlocks, 256, 0, stream>>>(bufB, W2, dinv, bufA);
    k_agg<<<aggBlocks, 256, 0, stream>>>(bufA, dinv, offs, csr_src, b2, bufB);
    // layer 3 (K=96)
    k_mm_h<HIDDEN><<<mmBlocks, 256, 0, stream>>>(bufB, W3, dinv, bufA);
    k_agg<<<aggBlocks, 256, 0, stream>>>(bufA, dinv, offs, csr_src, b3, bufB);

    k_pool<<<N_GRAPHS * POOL_SLICES, 192, 0, stream>>>(bufB, bat, pooled);
    k_head_mlp<<<N_GRAPHS, 128, 0, stream>>>(pooled, bat, lw1, lb1, lw2, lb2, out);
}

// Round 9
// 215.454 us; speedup vs baseline: 1.2811x; 1.2811x over previous
//
#include <hip/hip_runtime.h>
#include <hip/hip_fp16.h>

#define N_NODES 50000
#define N_EDGES 800000
#define D_FEAT 128
#define HIDDEN 96
#define N_CLASSES 10
#define N_GRAPHS 64
#define POOL_SLICES 16
#define SCAN_BLOCKS ((N_NODES + 255) / 256)   // 196

union F4H8 { float4 f; __half2 h[4]; };

typedef __attribute__((ext_vector_type(8))) _Float16 half8;
typedef __attribute__((ext_vector_type(4))) float f32x4;

// ---------------- graph preprocessing ----------------

__global__ void k_init(int* __restrict__ deg_i, float* __restrict__ pooled) {
    int i = blockIdx.x * 256 + threadIdx.x;
    if (i < N_NODES) deg_i[i] = 0;
    if (i < N_GRAPHS * HIDDEN) pooled[i] = 0.f;
}

__global__ void k_deg(const int* __restrict__ dst, int* __restrict__ deg_i,
                      int* __restrict__ rank) {
    int e = blockIdx.x * 256 + threadIdx.x;
    if (e < N_EDGES) rank[e] = atomicAdd(&deg_i[dst[e]], 1);
}

__global__ __launch_bounds__(256) void k_partial(const int* __restrict__ deg_i,
                                                 int* __restrict__ bsum) {
    __shared__ int wsum[4];
    int i = blockIdx.x * 256 + threadIdx.x;
    int v = (i < N_NODES) ? deg_i[i] : 0;
    for (int o = 32; o > 0; o >>= 1) v += __shfl_down(v, o, 64);
    int lane = threadIdx.x & 63, wid = threadIdx.x >> 6;
    if (lane == 0) wsum[wid] = v;
    __syncthreads();
    if (threadIdx.x == 0) bsum[blockIdx.x] = wsum[0] + wsum[1] + wsum[2] + wsum[3];
}

__global__ __launch_bounds__(256) void k_scanblk(const int* __restrict__ bsum,
                                                 int* __restrict__ bpre) {
    __shared__ int s[256];
    int t = threadIdx.x;
    s[t] = (t < SCAN_BLOCKS) ? bsum[t] : 0;
    __syncthreads();
    for (int off = 1; off < 256; off <<= 1) {
        int v = s[t];
        int a = (t >= off) ? s[t - off] : 0;
        __syncthreads();
        s[t] = v + a;
        __syncthreads();
    }
    if (t <= SCAN_BLOCKS) bpre[t] = (t == 0) ? 0 : s[t - 1];  // exclusive
}

__global__ __launch_bounds__(256) void k_offs(const int* __restrict__ deg_i,
                                              const int* __restrict__ bpre,
                                              int* __restrict__ offs,
                                              float* __restrict__ dinv) {
    __shared__ int s[256];
    int t = threadIdx.x;
    int i = blockIdx.x * 256 + t;
    int d = (i < N_NODES) ? deg_i[i] : 0;
    s[t] = d;
    __syncthreads();
    for (int off = 1; off < 256; off <<= 1) {
        int v = s[t];
        int a = (t >= off) ? s[t - off] : 0;
        __syncthreads();
        s[t] = v + a;
        __syncthreads();
    }
    int incl = s[t];
    int excl = incl - d;
    if (i < N_NODES) {
        int o = bpre[blockIdx.x] + excl;
        offs[i] = o;
        dinv[i] = rsqrtf((float)(d + 1));  // +1 self-loop
        if (i == N_NODES - 1) offs[N_NODES] = o + d;
    }
}

__global__ void k_fill(const int* __restrict__ src, const int* __restrict__ dst,
                       const int* __restrict__ rank, const int* __restrict__ offs,
                       int* __restrict__ csr_src) {
    int e = blockIdx.x * 256 + threadIdx.x;
    if (e >= N_EDGES) return;
    csr_src[offs[dst[e]] + rank[e]] = src[e];
}

// ---------------- MFMA matmul: hws = (h @ W) * dinv, fp16 out ----------------
// Block 256 thr = 4 waves; tile 64 nodes x 96 feats; wave w owns nodes w*16..+15.
// Per wave: 6 C-tiles (16x16), K/32 mfma steps of v_mfma_f32_16x16x32_f16.
// A (h) and B (W^T) staged fp16 in LDS with XOR chunk swizzle (c ^ (row&15))
// -> fragment reads conflict-free. C staged through LDS for coalesced stores.
// Fragment layouts (m89-verified family): A/B lane l -> row/col = l&15,
// k = (l>>4)*8 + [0..7] (+32*ks); C/D col = l&15, row = (l>>4)*4 + reg.

template <int K, bool F32IN>
__global__ __launch_bounds__(256) void k_mm_mfma(const void* __restrict__ hin,
                                                 const float* __restrict__ W,
                                                 const float* __restrict__ dinv,
                                                 __half* __restrict__ hws) {
    constexpr int CH = K / 8;        // 16B chunks per input row
    constexpr int KSTEPS = K / 32;
    __shared__ float4 Hl[64 * 16];   // 16KB: h tile, rows padded to 16 chunks
    __shared__ float4 Wt[96 * 16];   // 24KB: W^T fp16, f-rows padded to 16 chunks
    int t = threadIdx.x;
    int base = blockIdx.x * 64;

    // stage W^T fp16 swizzled: Wt[f][kc^ (f&15)][ke] = W[k][f]
    _Float16* WtH = (_Float16*)Wt;
    for (int idx = t; idx < K * 96; idx += 256) {
        int k = idx / 96, f = idx % 96;
        int kc = k >> 3, ke = k & 7;
        WtH[(f * 16 + (kc ^ (f & 15))) * 8 + ke] = (_Float16)W[idx];
    }
    // stage h tile fp16 swizzled
    if (F32IN) {
        const float4* x4 = (const float4*)hin;
        for (int idx = t; idx < 64 * CH; idx += 256) {
            int row = idx / CH, c = idx % CH;
            int gr = base + row; if (gr >= N_NODES) gr = N_NODES - 1;
            float4 a = x4[(size_t)gr * (CH * 2) + c * 2];
            float4 b = x4[(size_t)gr * (CH * 2) + c * 2 + 1];
            F4H8 o;
            o.h[0] = __floats2half2_rn(a.x, a.y);
            o.h[1] = __floats2half2_rn(a.z, a.w);
            o.h[2] = __floats2half2_rn(b.x, b.y);
            o.h[3] = __floats2half2_rn(b.z, b.w);
            Hl[row * 16 + (c ^ (row & 15))] = o.f;
        }
    } else {
        const float4* h4 = (const float4*)hin;
        for (int idx = t; idx < 64 * CH; idx += 256) {
            int row = idx / CH, c = idx % CH;
            int gr = base + row; if (gr >= N_NODES) gr = N_NODES - 1;
            Hl[row * 16 + (c ^ (row & 15))] = h4[(size_t)gr * CH + c];
        }
    }
    __syncthreads();

    int w = t >> 6, l = t & 63;
    int lr = l & 15, lq = l >> 4;
    int arow = w * 16 + lr;          // arow & 15 == lr
    f32x4 acc[6];
    #pragma unroll
    for (int i = 0; i < 6; ++i) acc[i] = (f32x4){0.f, 0.f, 0.f, 0.f};

    #pragma unroll
    for (int ks = 0; ks < KSTEPS; ++ks) {
        int ck = ks * 4 + lq;
        half8 a = *(const half8*)&Hl[arow * 16 + (ck ^ lr)];
        #pragma unroll
        for (int tf = 0; tf < 6; ++tf) {
            int f = tf * 16 + lr;    // f & 15 == lr
            half8 b = *(const half8*)&Wt[f * 16 + (ck ^ lr)];
            acc[tf] = __builtin_amdgcn_mfma_f32_16x16x32_f16(a, b, acc[tf], 0, 0, 0);
        }
    }

    // dinv for this lane's 4 C rows
    float dv[4];
    #pragma unroll
    for (int j = 0; j < 4; ++j) {
        int n = base + w * 16 + lq * 4 + j;
        if (n >= N_NODES) n = N_NODES - 1;
        dv[j] = dinv[n];
    }
    __syncthreads();                 // all waves done reading Hl
    _Float16* C = (_Float16*)Hl;     // reuse as [64][96] fp16
    #pragma unroll
    for (int tf = 0; tf < 6; ++tf)
        #pragma unroll
        for (int j = 0; j < 4; ++j)
            C[(w * 16 + lq * 4 + j) * 96 + tf * 16 + lr] =
                (_Float16)(acc[tf][j] * dv[j]);
    __syncthreads();
    // coalesced copy-out: 64 rows x 12 float4
    const float4* C4 = (const float4*)C;
    for (int idx = t; idx < 64 * 12; idx += 256) {
        int row = idx / 12;
        int n = base + row;
        if (n < N_NODES)
            ((float4*)hws)[(size_t)n * 12 + (idx % 12)] = C4[idx];
    }
}

// ------------- aggregation: h_out[n] = relu(b + dinv[n]*(hws[n] + sum_in hws[s])) -------------

__global__ __launch_bounds__(256) void k_agg(const __half* __restrict__ hws,
                                             const float* __restrict__ dinv,
                                             const int* __restrict__ offs,
                                             const int* __restrict__ csr_src,
                                             const float* __restrict__ bias,
                                             __half* __restrict__ hout) {
    int id = blockIdx.x * 256 + threadIdx.x;
    if (id >= N_NODES * 12) return;
    int c = id % 12;
    int n = id / 12;
    const float4* hw4 = (const float4*)hws;
    F4H8 v;
    v.f = hw4[(size_t)n * 12 + c];   // self-loop (already dinv[n]-scaled)
    float2 p0 = __half22float2(v.h[0]), p1 = __half22float2(v.h[1]);
    float2 p2 = __half22float2(v.h[2]), p3 = __half22float2(v.h[3]);
    float4 A = make_float4(p0.x, p0.y, p1.x, p1.y);
    float4 B = make_float4(p2.x, p2.y, p3.x, p3.y);

    int beg = offs[n], end = offs[n + 1];
    int i = beg;
    for (; i + 2 <= end; i += 2) {
        F4H8 v0, v1;
        v0.f = hw4[(size_t)csr_src[i] * 12 + c];
        v1.f = hw4[(size_t)csr_src[i + 1] * 12 + c];
        float2 a0 = __half22float2(v0.h[0]), a1 = __half22float2(v0.h[1]);
        float2 a2 = __half22float2(v0.h[2]), a3 = __half22float2(v0.h[3]);
        float2 b0 = __half22float2(v1.h[0]), b1 = __half22float2(v1.h[1]);
        float2 b2 = __half22float2(v1.h[2]), b3 = __half22float2(v1.h[3]);
        A.x += a0.x + b0.x; A.y += a0.y + b0.y;
        A.z += a1.x + b1.x; A.w += a1.y + b1.y;
        B.x += a2.x + b2.x; B.y += a2.y + b2.y;
        B.z += a3.x + b3.x; B.w += a3.y + b3.y;
    }
    if (i < end) {
        F4H8 v0;
        v0.f = hw4[(size_t)csr_src[i] * 12 + c];
        float2 a0 = __half22float2(v0.h[0]), a1 = __half22float2(v0.h[1]);
        float2 a2 = __half22float2(v0.h[2]), a3 = __half22float2(v0.h[3]);
        A.x += a0.x; A.y += a0.y; A.z += a1.x; A.w += a1.y;
        B.x += a2.x; B.y += a2.y; B.z += a3.x; B.w += a3.y;
    }

    float di = dinv[n];
    float4 b0 = ((const float4*)bias)[c * 2];
    float4 b1 = ((const float4*)bias)[c * 2 + 1];
    A.x = fmaxf(A.x * di + b0.x, 0.f); A.y = fmaxf(A.y * di + b0.y, 0.f);
    A.z = fmaxf(A.z * di + b0.z, 0.f); A.w = fmaxf(A.w * di + b0.w, 0.f);
    B.x = fmaxf(B.x * di + b1.x, 0.f); B.y = fmaxf(B.y * di + b1.y, 0.f);
    B.z = fmaxf(B.z * di + b1.z, 0.f); B.w = fmaxf(B.w * di + b1.w, 0.f);

    F4H8 o;
    o.h[0] = __floats2half2_rn(A.x, A.y);
    o.h[1] = __floats2half2_rn(A.z, A.w);
    o.h[2] = __floats2half2_rn(B.x, B.y);
    o.h[3] = __floats2half2_rn(B.z, B.w);
    ((float4*)hout)[(size_t)n * 12 + c] = o.f;
}

// ------------- parallel mean-pool: 64 graphs x 16 slices (fp16 input) -------------

__global__ __launch_bounds__(192) void k_pool(const __half* __restrict__ h,
                                              const int* __restrict__ batch,
                                              float* __restrict__ pooled) {
    int g = blockIdx.x / POOL_SLICES;
    int slice = blockIdx.x % POOL_SLICES;
    int t = threadIdx.x;
    int f = t % HIDDEN;
    int j = t / HIDDEN;  // 0 or 1
    int lo = 0, hi = N_NODES;
    while (lo < hi) { int m = (lo + hi) >> 1; if (batch[m] < g) lo = m + 1; else hi = m; }
    int start = lo;
    hi = N_NODES;
    while (lo < hi) { int m = (lo + hi) >> 1; if (batch[m] < g + 1) lo = m + 1; else hi = m; }
    int end = lo;
    int len = end - start;
    int per = (len + POOL_SLICES - 1) / POOL_SLICES;
    int s0 = start + slice * per;
    int s1 = min(s0 + per, end);
    float acc = 0.f;
    for (int n = s0 + j; n < s1; n += 2) acc += __half2float(h[(size_t)n * HIDDEN + f]);
    atomicAdd(&pooled[g * HIDDEN + f], acc);
}

// ------------- MLP head, one block per graph -------------

__global__ __launch_bounds__(128) void k_head_mlp(const float* __restrict__ pooled_in,
                                                  const int* __restrict__ batch,
                                                  const float* __restrict__ lw1,
                                                  const float* __restrict__ lb1,
                                                  const float* __restrict__ lw2,
                                                  const float* __restrict__ lb2,
                                                  float* __restrict__ out) {
    __shared__ float pooled[HIDDEN];
    __shared__ float zbuf[HIDDEN];
    int g = blockIdx.x;
    int t = threadIdx.x;
    int lo = 0, hi = N_NODES;
    while (lo < hi) { int m = (lo + hi) >> 1; if (batch[m] < g) lo = m + 1; else hi = m; }
    int start = lo;
    hi = N_NODES;
    while (lo < hi) { int m = (lo + hi) >> 1; if (batch[m] < g + 1) lo = m + 1; else hi = m; }
    int end = lo;
    float cnt = fmaxf((float)(end - start), 1.f);
    if (t < HIDDEN) pooled[t] = pooled_in[g * HIDDEN + t] / cnt;
    __syncthreads();
    if (t < HIDDEN) {
        float a = lb1[t];
        for (int k = 0; k < HIDDEN; ++k) a += pooled[k] * lw1[k * HIDDEN + t];
        zbuf[t] = fmaxf(a, 0.f);
    }
    __syncthreads();
    if (t < N_CLASSES) {
        float a = lb2[t];
        for (int k = 0; k < HIDDEN; ++k) a += zbuf[k] * lw2[k * N_CLASSES + t];
        out[g * N_CLASSES + t] = a;
    }
}

// ---------------- launch ----------------

extern "C" void kernel_launch(void* const* d_in, const int* in_sizes, int n_in,
                              void* d_out, int out_size, void* d_ws, size_t ws_size,
                              hipStream_t stream) {
    const float* x   = (const float*)d_in[0];
    const int*   ei  = (const int*)d_in[1];   // [2, E]
    const int*   bat = (const int*)d_in[2];
    const float* W1  = (const float*)d_in[3];
    const float* b1  = (const float*)d_in[4];
    const float* W2  = (const float*)d_in[5];
    const float* b2  = (const float*)d_in[6];
    const float* W3  = (const float*)d_in[7];
    const float* b3  = (const float*)d_in[8];
    const float* lw1 = (const float*)d_in[9];
    const float* lb1 = (const float*)d_in[10];
    const float* lw2 = (const float*)d_in[11];
    const float* lb2 = (const float*)d_in[12];
    float* out = (float*)d_out;

    const int* src = ei;
    const int* dst = ei + N_EDGES;

    // workspace carve-up (256B aligned)
    char* ws = (char*)d_ws;
    size_t off = 0;
    auto alloc = [&](size_t bytes) {
        size_t p = off;
        off = (off + bytes + 255) & ~(size_t)255;
        return p;
    };
    float*  dinv    = (float*) (ws + alloc(sizeof(float) * N_NODES));
    int*    deg_i   = (int*)   (ws + alloc(sizeof(int) * N_NODES));
    int*    offs    = (int*)   (ws + alloc(sizeof(int) * (N_NODES + 1)));
    int*    bsum    = (int*)   (ws + alloc(sizeof(int) * (SCAN_BLOCKS + 1)));
    int*    bpre    = (int*)   (ws + alloc(sizeof(int) * (SCAN_BLOCKS + 1)));
    int*    rank    = (int*)   (ws + alloc(sizeof(int) * N_EDGES));
    int*    csr_src = (int*)   (ws + alloc(sizeof(int) * N_EDGES));
    __half* bufA    = (__half*)(ws + alloc(sizeof(__half) * (size_t)N_NODES * HIDDEN));
    __half* bufB    = (__half*)(ws + alloc(sizeof(__half) * (size_t)N_NODES * HIDDEN));
    float*  pooled  = (float*) (ws + alloc(sizeof(float) * N_GRAPHS * HIDDEN));
    (void)ws_size;

    const int nodeBlocks = (N_NODES + 255) / 256;
    const int edgeBlocks = (N_EDGES + 255) / 256;
    const int mmBlocks   = (N_NODES + 63) / 64;           // 782
    const int aggBlocks  = (N_NODES * 12 + 255) / 256;    // 2344

    k_init<<<nodeBlocks, 256, 0, stream>>>(deg_i, pooled);
    k_deg<<<edgeBlocks, 256, 0, stream>>>(dst, deg_i, rank);
    k_partial<<<SCAN_BLOCKS, 256, 0, stream>>>(deg_i, bsum);
    k_scanblk<<<1, 256, 0, stream>>>(bsum, bpre);
    k_offs<<<SCAN_BLOCKS, 256, 0, stream>>>(deg_i, bpre, offs, dinv);
    k_fill<<<edgeBlocks, 256, 0, stream>>>(src, dst, rank, offs, csr_src);

    // layer 1 (K=128, f32 input staged->fp16 in LDS)
    k_mm_mfma<D_FEAT, true><<<mmBlocks, 256, 0, stream>>>(x, W1, dinv, bufA);
    k_agg<<<aggBlocks, 256, 0, stream>>>(bufA, dinv, offs, csr_src, b1, bufB);
    // layer 2 (K=96, fp16 input)
    k_mm_mfma<HIDDEN, false><<<mmBlocks, 256, 0, stream>>>(bufB, W2, dinv, bufA);
    k_agg<<<aggBlocks, 256, 0, stream>>>(bufA, dinv, offs, csr_src, b2, bufB);
    // layer 3 (K=96, fp16 input)
    k_mm_mfma<HIDDEN, false><<<mmBlocks, 256, 0, stream>>>(bufB, W3, dinv, bufA);
    k_agg<<<aggBlocks, 256, 0, stream>>>(bufA, dinv, offs, csr_src, b3, bufB);

    k_pool<<<N_GRAPHS * POOL_SLICES, 192, 0, stream>>>(bufB, bat, pooled);
    k_head_mlp<<<N_GRAPHS, 128, 0, stream>>>(pooled, bat, lw1, lb1, lw2, lb2, out);
}